// Round 2
// baseline (967.169 us; speedup 1.0000x reference)
//
#include <hip/hip_runtime.h>

typedef unsigned short ushort_t;
typedef unsigned int uint_t;
typedef __bf16 v8bf __attribute__((ext_vector_type(8)));
typedef float v4f __attribute__((ext_vector_type(4)));

#define DTC 0.1f
#define NB 32768
#define NT 50

union U8 { v8bf v; ushort_t s[8]; };

__device__ __forceinline__ ushort_t f2bf(float f) {
  uint_t u = __float_as_uint(f);
  u += 0x7fffu + ((u >> 16) & 1u);   // RNE
  return (ushort_t)(u >> 16);
}
__device__ __forceinline__ float bf2f(ushort_t s) {
  return __uint_as_float(((uint_t)s) << 16);
}
__device__ __forceinline__ float sigm(float x) {
  return __builtin_amdgcn_rcpf(1.f + __expf(-x));
}
__device__ __forceinline__ float tanhf_(float x) {
  return 1.f - 2.f * __builtin_amdgcn_rcpf(1.f + __expf(2.f * x));
}

// Opacity barrier: forces a built fragment to stay resident in registers and
// blocks remat of the (invariant-load + f2bf pack) chain into the t-loop.
__device__ __forceinline__ v8bf opaque(v8bf x) {
  union { v8bf v; uint_t u[4]; } t; t.v = x;
  asm volatile("" : "+v"(t.u[0]), "+v"(t.u[1]), "+v"(t.u[2]), "+v"(t.u[3]));
  return t.v;
}

// ROUND THEORY (2nd resubmit — GPU timeouts, never benched):
// 1197 us == 28.7 Kcyc/CU-step vs round-3's 29.6 Kcyc => the opaque +
// waves_per_eu(2,2) fix only moved 3%; the per-step weight re-fetch (spill or
// remat, ~600 KB/WG/step from L2, invisible in FETCH_SIZE) is still there.
// Persistent reg demand (Uf64+Ef16+W123f48+base_pk32+c_st16 ~ 176) + working
// set sits at the 256-VGPR cap. Fix: W1/W2/W3 move to LDS as prebuilt
// per-thread fragments (linear [kc][tid][8] layout -> conflict-free b128
// read/write), freeing 48 VGPRs so the rest truly fits. gfx950 LDS/WG limit
// is 160 KiB; total here = 162368 B <= 163840 B.
//
// LDS layout (shorts), total 81184 sh = 162368 B:
//  h_s : [64][136] @ 0      (8704)   | pe[64][200]=12800 aliases h_s+xa_s (pre-loop only)
//  xa_s: [64][136] @ 8704   (8704)
//  xb_s: [64][136] @ 17408  (8704)   | part[512 f32] aliases xb_s (act phase only)
//  ex_s: [64][40]  @ 26112  (2560)
//  sdf : [2][640] f32 @ 28672 (2560)   idm/mcs prefetch double buffer
//  carr: 256 f32   @ 31232  (512)    [v|x|d|act] x64
//  wa  : 128 f32   @ 31744  (256)
//  nrm : 16  f32   @ 32000  (32)
//  w1_l: [4][512][8] bf16 @ 32032 (16384)  per-thread MFMA B-fragments, linear
//  w2_l: @ 48416 (16384)
//  w3_l: @ 64800 (16384)

__global__ __launch_bounds__(512) __attribute__((amdgpu_waves_per_eu(2, 2)))
void fsim_kernel(
    const float* __restrict__ proj, const float* __restrict__ ench,
    const float* __restrict__ idm,  const float* __restrict__ mcs,
    const float* __restrict__ smean,const float* __restrict__ svar,
    const float* __restrict__ Wl,   const float* __restrict__ Ul,
    const float* __restrict__ bl,   const float* __restrict__ W1,
    const float* __restrict__ b1,   const float* __restrict__ W2,
    const float* __restrict__ b2,   const float* __restrict__ W3,
    const float* __restrict__ b3,   const float* __restrict__ Wa,
    const float* __restrict__ ba,   float* __restrict__ out) {
  __shared__ __align__(16) short sh[81184];
  short* pe   = sh;                      // aliases h_s+xa_s, pre-loop only
  short* h_s  = sh;
  short* xa_s = sh + 8704;
  short* xb_s = sh + 17408;
  short* ex_s = sh + 26112;
  float* sdf  = (float*)(sh + 28672);
  float* carr = (float*)(sh + 31232);
  float* wa_s = (float*)(sh + 31744);
  float* nrm  = (float*)(sh + 32000);
  float* part = (float*)(sh + 17408);    // aliases xb_s, act phase only
  short* w1_l = sh + 32032;
  short* w2_l = sh + 48416;
  short* w3_l = sh + 64800;

  const int tid  = threadIdx.x;
  const int wg   = blockIdx.x;
  const int w    = tid >> 6;
  const int l    = tid & 63;
  const int quad = l >> 4;
  const int c16  = l & 15;
  const int colz = w * 16 + c16;   // unit / MLP column owned by this lane

  float* out_disp = out;
  float* out_act  = out + (size_t)NB * NT;

  // ---- prefetch addressing hoisted out of the t-loop; T14 issue/write split ----
  // i = e*10 + f, i in [0,640): f<7 -> idm cols {0..5,10}, else mcs cols 0..2
  const int eA = tid / 10, fA = tid - eA * 10;
  const float* pfpA; int pstA;
  if (fA < 7) { pfpA = idm + (size_t)(wg * 64 + eA) * 550 + ((fA == 6) ? 10 : fA); pstA = 11; }
  else        { pfpA = mcs + (size_t)(wg * 64 + eA) * 150 + (fA - 7);              pstA = 3;  }
  const int iB = tid + 512;                 // only valid/used for tid < 128
  const int eB = iB / 10, fB = iB - eB * 10;
  const float* pfpB; int pstB;
  if (fB < 7) { pfpB = idm + (size_t)(wg * 64 + eB) * 550 + ((fB == 6) ? 10 : fB); pstB = 11; }
  else        { pfpB = mcs + (size_t)(wg * 64 + eB) * 150 + (fB - 7);              pstB = 3;  }
  float pfA = pfpA[0];
  float pfB = (tid < 128) ? pfpB[0] : 0.f;

  // ---------------- persistent B fragments kept in VGPRs ----------------
  v8bf Uf[4][4];   // [kc][gate]
#pragma unroll
  for (int kc = 0; kc < 4; ++kc) {
#pragma unroll
    for (int g = 0; g < 4; ++g) {
      U8 u;
#pragma unroll
      for (int j = 0; j < 8; ++j)
        u.s[j] = f2bf(Ul[(kc * 32 + quad * 8 + j) * 512 + g * 128 + colz]);
      Uf[kc][g] = opaque(u.v);
    }
  }
  // env/mc chunk with hi/lo split: k 0..8 -> Whi, 9..17 -> Wlo, 18..26 -> Whi
  v8bf Ef[4];
#pragma unroll
  for (int g = 0; g < 4; ++g) {
    U8 u;
#pragma unroll
    for (int j = 0; j < 8; ++j) {
      int kk = quad * 8 + j;
      ushort_t val = 0;
      if (kk < 27) {
        int jj = kk % 9;
        float wv = Wl[(192 + jj) * 512 + g * 128 + colz];
        ushort_t hi = f2bf(wv);
        val = (kk < 9) ? hi : ((kk < 18) ? f2bf(wv - bf2f(hi)) : hi);
      }
      u.s[j] = val;
    }
    Ef[g] = opaque(u.v);
  }

  // ---- W1/W2/W3 fragments -> LDS (per-thread prebuilt, linear = conflict-free) ----
#pragma unroll
  for (int kc = 0; kc < 4; ++kc) {
    U8 a, b, c;
#pragma unroll
    for (int j = 0; j < 8; ++j) {
      int row = kc * 32 + quad * 8 + j;
      a.s[j] = f2bf(W1[row * 128 + colz]);
      b.s[j] = f2bf(W2[row * 128 + colz]);
      c.s[j] = f2bf(W3[row * 128 + colz]);
    }
    *(v8bf*)(w1_l + (kc * 512 + tid) * 8) = a.v;
    *(v8bf*)(w2_l + (kc * 512 + tid) * 8) = b.v;
    *(v8bf*)(w3_l + (kc * 512 + tid) * 8) = c.v;
  }

  float bias1 = b1[colz], bias2 = b2[colz], bias3 = b3[colz];
  float ba_v  = ba[0];

  // ---------------- LDS setup + t=0 prefetch store + [proj|enc] staging ----------------
  for (int i = tid; i < 2560; i += 512) ex_s[i] = 0;  // zero (covers pad k=27..31)
  if (tid < 6) { nrm[tid] = smean[tid]; nrm[6 + tid] = 1.f / sqrtf(svar[tid]); }
  if (tid < 128) wa_s[tid] = Wa[tid];
  sdf[tid] = pfA;                       // buffer 0 = t=0 features
  if (tid < 128) sdf[512 + tid] = pfB;

  for (int i = tid; i < 64 * 192; i += 512) {
    int e = i / 192, j = i - e * 192;
    float v = (j < 64) ? proj[(wg * 64 + e) * 64 + j]
                       : ench[(wg * 64 + e) * 128 + (j - 64)];
    pe[e * 200 + j] = (short)f2bf(v);
  }
  __syncthreads();

  // ------- base_z = b_lstm + [proj|enc] @ W_lstm[0:192], packed bf16 in regs ------
  uint_t base_pk[4][8];
#pragma unroll
  for (int mt = 0; mt < 4; ++mt) {
    v4f accz[4];
#pragma unroll
    for (int g = 0; g < 4; ++g) {
      float bz = bl[g * 128 + colz];
      accz[g] = (v4f){bz, bz, bz, bz};
    }
    for (int kc = 0; kc < 6; ++kc) {
      const v8bf a = *(const v8bf*)(pe + (mt * 16 + c16) * 200 + kc * 32 + quad * 8);
#pragma unroll
      for (int g = 0; g < 4; ++g) {
        U8 bu;
#pragma unroll
        for (int j = 0; j < 8; ++j)
          bu.s[j] = f2bf(Wl[(kc * 32 + quad * 8 + j) * 512 + g * 128 + colz]);
        accz[g] = __builtin_amdgcn_mfma_f32_16x16x32_bf16(a, bu.v, accz[g], 0, 0, 0);
      }
    }
#pragma unroll
    for (int g = 0; g < 4; ++g) {
      base_pk[mt][g * 2 + 0] = (uint_t)f2bf(accz[g][0]) | ((uint_t)f2bf(accz[g][1]) << 16);
      base_pk[mt][g * 2 + 1] = (uint_t)f2bf(accz[g][2]) | ((uint_t)f2bf(accz[g][3]) << 16);
    }
  }
  __syncthreads();  // pe reads done; region reusable as h_s/xa_s

  // zero h_s so the h @ U_lstm GEMM is branch-free at t=0 (h0 == 0)
  for (int i = tid; i < 8704; i += 512) h_s[i] = 0;

  v4f c_st[4];
#pragma unroll
  for (int mt = 0; mt < 4; ++mt) c_st[mt] = (v4f){0.f, 0.f, 0.f, 0.f};
  // first GEMM1 read of h_s is after bar1 below, so the zeroing is synced.

  for (int t = 0; t < NT; ++t) {
    // ---- issue next-step idm/mcs loads early; LDS-write happens at step end ----
    if (t + 1 < NT) {
      pfA = pfpA[(size_t)(t + 1) * pstA];
      if (tid < 128) pfB = pfpB[(size_t)(t + 1) * pstB];
    }

    // ------- phase A: per-element carries + env features (wave 0, LDS-only reads) ----
    if (w == 0) {
      const int e  = l;
      const int ge = wg * 64 + e;
      const float* sp = sdf + (t & 1) * 640 + e * 10;
      float s0 = sp[0], s1 = sp[1], s2 = sp[2], s3 = sp[3];
      float s4 = sp[4], s5 = sp[5], s10 = sp[6];
      float mc0 = sp[7], mc1 = sp[8], mc2 = sp[9];
      float pa = 0.f, vv = 0.f, xx = 0.f, dd = 0.f;
      if (t != 0) { pa = carr[192 + e]; vv = carr[e]; xx = carr[64 + e]; dd = carr[128 + e]; }
      float new_v = (t == 0) ? s0 : vv + pa * DTC;
      float delta = new_v * DTC + 0.5f * pa * DTC * DTC;
      float new_x = (t == 0) ? s3 : xx + delta;
      float new_d = (t == 0) ? 0.f : dd + delta;
      float env[9];
      env[0] = new_v;
      env[1] = s1;
      env[2] = new_v - s1;
      env[3] = s4 - new_x;
      env[4] = (new_v - s2) * s10;
      env[5] = (s5 - new_x) * s10 + (1.f - s10) * 100.f;
#pragma unroll
      for (int j = 0; j < 6; ++j) env[j] = (env[j] - nrm[j]) * nrm[6 + j];
      env[6] = mc0; env[7] = mc1; env[8] = mc2;
#pragma unroll
      for (int j = 0; j < 9; ++j) {
        ushort_t hi = f2bf(env[j]);
        ushort_t lo = f2bf(env[j] - bf2f(hi));
        ex_s[e * 40 + j]      = (short)hi;
        ex_s[e * 40 + 9 + j]  = (short)hi;
        ex_s[e * 40 + 18 + j] = (short)lo;
      }
      carr[e] = new_v; carr[64 + e] = new_x; carr[128 + e] = new_d;
      out_disp[(size_t)ge * NT + t] = new_d;
    }
    __syncthreads();  // bar1: ex_s (and zeroed/previous h_s) ready

    // ------- GEMM1 (z) + gates, per m-tile -------
    v4f h2v[4];
#pragma unroll
    for (int mt = 0; mt < 4; ++mt) {
      v4f acc[4];
#pragma unroll
      for (int g = 0; g < 4; ++g) {   // init from packed base
        uint_t w0 = base_pk[mt][g * 2 + 0], w1 = base_pk[mt][g * 2 + 1];
        acc[g][0] = __uint_as_float(w0 << 16);
        acc[g][1] = __uint_as_float(w0 & 0xffff0000u);
        acc[g][2] = __uint_as_float(w1 << 16);
        acc[g][3] = __uint_as_float(w1 & 0xffff0000u);
      }
#pragma unroll
      for (int kc = 0; kc < 4; ++kc) {   // h @ U_lstm (h_s zeroed at t==0)
        const v8bf a = *(const v8bf*)(h_s + (mt * 16 + c16) * 136 + kc * 32 + quad * 8);
#pragma unroll
        for (int g = 0; g < 4; ++g)
          acc[g] = __builtin_amdgcn_mfma_f32_16x16x32_bf16(a, Uf[kc][g], acc[g], 0, 0, 0);
      }
      {  // env/mc hi-lo chunk
        const v8bf ax = *(const v8bf*)(ex_s + (mt * 16 + c16) * 40 + quad * 8);
#pragma unroll
        for (int g = 0; g < 4; ++g)
          acc[g] = __builtin_amdgcn_mfma_f32_16x16x32_bf16(ax, Ef[g], acc[g], 0, 0, 0);
      }
      v4f cc = c_st[mt], h2;
#pragma unroll
      for (int r = 0; r < 4; ++r) {
        float ig = sigm(acc[0][r]);
        float fg = sigm(acc[1][r]);
        float gg = tanhf_(acc[2][r]);
        float og = sigm(acc[3][r]);
        float c2 = fg * cc[r] + ig * gg;
        cc[r] = c2;
        h2[r] = og * tanhf_(c2);
      }
      c_st[mt] = cc;
      h2v[mt]  = h2;
    }
    __syncthreads();  // bar2: all h_s / ex_s reads done
#pragma unroll
    for (int mt = 0; mt < 4; ++mt)
#pragma unroll
      for (int r = 0; r < 4; ++r)
        h_s[(mt * 16 + quad * 4 + r) * 136 + colz] = (short)f2bf(h2v[mt][r]);
    __syncthreads();  // bar3: h2 visible

    // ------- MLP: 3 x (128x128) with lrelu; B-fragments from LDS -------
    auto mlp_layer = [&](const short* S, const short* WL, float bias, short* D) {
      v8bf Wf[4];
#pragma unroll
      for (int kc = 0; kc < 4; ++kc)
        Wf[kc] = *(const v8bf*)(WL + (kc * 512 + tid) * 8);   // linear, conflict-free
      v4f xs[4];
#pragma unroll
      for (int mt = 0; mt < 4; ++mt) {
        v4f acc = (v4f){bias, bias, bias, bias};
#pragma unroll
        for (int kc = 0; kc < 4; ++kc) {
          const v8bf a = *(const v8bf*)(S + (mt * 16 + c16) * 136 + kc * 32 + quad * 8);
          acc = __builtin_amdgcn_mfma_f32_16x16x32_bf16(a, Wf[kc], acc, 0, 0, 0);
        }
#pragma unroll
        for (int r = 0; r < 4; ++r) { float v = acc[r]; acc[r] = (v > 0.f) ? v : 0.3f * v; }
        xs[mt] = acc;
      }
#pragma unroll
      for (int mt = 0; mt < 4; ++mt)
#pragma unroll
        for (int r = 0; r < 4; ++r)
          D[(mt * 16 + quad * 4 + r) * 136 + colz] = (short)f2bf(xs[mt][r]);
    };
    mlp_layer(h_s, w1_l, bias1, xa_s);
    __syncthreads();  // bar4
    mlp_layer(xa_s, w2_l, bias2, xb_s);
    __syncthreads();  // bar5
    mlp_layer(xb_s, w3_l, bias3, xa_s);
    __syncthreads();  // bar6: x3 in xa_s; xb_s free -> part

    // ------- act = x3 @ Wa + ba -------
    {
      int e = tid >> 3, p = tid & 7;
      float s = 0.f;
#pragma unroll
      for (int i = 0; i < 16; ++i) {
        int u = p * 16 + i;
        s += bf2f((ushort_t)xa_s[e * 136 + u]) * wa_s[u];
      }
      part[e * 8 + p] = s;
    }
    // ---- write prefetched t+1 features late (vmcnt wait hidden by the step) ----
    if (t + 1 < NT) {
      sdf[((t + 1) & 1) * 640 + tid] = pfA;
      if (tid < 128) sdf[((t + 1) & 1) * 640 + 512 + tid] = pfB;
    }
    __syncthreads();  // bar7
    if (tid < 64) {
      float a = ba_v;
#pragma unroll
      for (int p = 0; p < 8; ++p) a += part[tid * 8 + p];
      carr[192 + tid] = a;  // prev_act for next step
      out_act[(size_t)(wg * 64 + tid) * NT + t] = a;
    }
  }
}

extern "C" void kernel_launch(void* const* d_in, const int* in_sizes, int n_in,
                              void* d_out, int out_size, void* d_ws, size_t ws_size,
                              hipStream_t stream) {
  (void)in_sizes; (void)n_in; (void)out_size; (void)d_ws; (void)ws_size;
  fsim_kernel<<<dim3(512), dim3(512), 0, stream>>>(
      (const float*)d_in[0],  (const float*)d_in[1],  (const float*)d_in[2],
      (const float*)d_in[3],  (const float*)d_in[4],  (const float*)d_in[5],
      (const float*)d_in[6],  (const float*)d_in[7],  (const float*)d_in[8],
      (const float*)d_in[9],  (const float*)d_in[10], (const float*)d_in[11],
      (const float*)d_in[12], (const float*)d_in[13], (const float*)d_in[14],
      (const float*)d_in[15], (const float*)d_in[16], (float*)d_out);
}